// Round 10
// baseline (833.480 us; speedup 1.0000x reference)
//
#include <hip/hip_runtime.h>
#include <math.h>

#define B_   16
#define T_   60
#define LMD  63
#define IH   240
#define IW   320
#define XDIM 316
#define NSEQ 960

#define X_BYTES   1213440                   // 960*316*4
#define G_BYTES   983040                    // 960*256*4

__device__ __forceinline__ float rl(float v, int k) {
    return __uint_as_float((unsigned)__builtin_amdgcn_readlane((int)__float_as_uint(v), k));
}
// Fast gates (v_exp + v_rcp): verified R21 — absmax identical to libm (9.5e-7).
__device__ __forceinline__ float sig_f(float x) {
    return __builtin_amdgcn_rcpf(1.0f + __expf(-x));
}
__device__ __forceinline__ float tanh_f(float x) {
    return 1.0f - 2.0f * __builtin_amdgcn_rcpf(__expf(2.0f * x) + 1.0f);
}

// ---------------------------------------------------------------- K1: f-MLP (LDS broadcast, 4 accum chains)
__global__ void k_mlp(const float* __restrict__ inp,
                      const float* __restrict__ W00, const float* __restrict__ b00,
                      const float* __restrict__ W01, const float* __restrict__ b01,
                      float* __restrict__ X) {
    __shared__ float x0s[LMD], f1s[LMD];
    int bt = blockIdx.x;
    int b = bt / T_, t = bt % T_;
    int s = t * B_ + b;
    int m = threadIdx.x;                 // 0..63
    if (m < LMD) x0s[m] = inp[bt * LMD + m];
    __syncthreads();
    if (m < LMD) {
        const float* wr = W00 + m * LMD;
        float a0 = 0.f, a1 = 0.f, a2 = 0.f, a3 = 0.f;
        for (int k = 0; k < 60; k += 4) {
            a0 += x0s[k + 0] * wr[k + 0];
            a1 += x0s[k + 1] * wr[k + 1];
            a2 += x0s[k + 2] * wr[k + 2];
            a3 += x0s[k + 3] * wr[k + 3];
        }
        a0 += x0s[60] * wr[60]; a1 += x0s[61] * wr[61]; a2 += x0s[62] * wr[62];
        f1s[m] = fmaxf(((a0 + a1) + (a2 + a3)) + b00[m], 0.f);
    }
    __syncthreads();
    {
        const float* wr = W01 + m * LMD;
        float a0 = 0.f, a1 = 0.f, a2 = 0.f, a3 = 0.f;
        for (int k = 0; k < 60; k += 4) {
            a0 += f1s[k + 0] * wr[k + 0];
            a1 += f1s[k + 1] * wr[k + 1];
            a2 += f1s[k + 2] * wr[k + 2];
            a3 += f1s[k + 3] * wr[k + 3];
        }
        a0 += f1s[60] * wr[60]; a1 += f1s[61] * wr[61]; a2 += f1s[62] * wr[62];
        X[(size_t)s * XDIM + m] = fmaxf(((a0 + a1) + (a2 + a3)) + b01[m], 0.f);
    }
}

// ---------------------------------------------------------------- K2: conv stack — video-load pipeline + wave ic-reduce
__global__ __launch_bounds__(256, 1) void k_conv(const float* __restrict__ video,
        const float* __restrict__ Wc0, const float* __restrict__ bc0,
        const float* __restrict__ Wc1, const float* __restrict__ bc1,
        const float* __restrict__ Wc2, const float* __restrict__ bc2,
        float* __restrict__ X) {
    __shared__ float W0T[26 * 16];         // [tap][ch]; row 25 = bc0
    __shared__ float band[16 * 408];       // [ic][d*80 + c0c]
    __shared__ float part[19 * 4 * 17];    // [c1c][wave][ch1], pad 17
    __shared__ float c1L[14 * 19 * 17];    // [(r1*19 + c1c)*17 + ch]
    int tid = threadIdx.x;
    int bt = blockIdx.x;
    int b = bt / T_, t = bt % T_;
    int s = t * B_ + b;
    const float* vid = video + (size_t)bt * (IH * IW);

    int ch1 = tid & 15, ic = tid >> 4;
    int wave = tid >> 6, lane = tid & 63;

    int d0 = tid / 79, c0c0 = tid % 79;
    int pos1 = tid + 256;
    bool has1 = (pos1 < 395);
    int d1 = has1 ? pos1 / 79 : 0, c0c1 = has1 ? pos1 % 79 : 0;

    for (int i = tid; i < 400; i += 256) { int ch = i / 25, tap = i % 25; W0T[tap * 16 + ch] = Wc0[i]; }
    if (tid < 16) W0T[25 * 16 + tid] = bc0[tid];
    float w1r[25];
#pragma unroll
    for (int tap = 0; tap < 25; ++tap)
        w1r[tap] = Wc1[(ch1 * 16 + ic) * 25 + tap];

    float PX0[25], PX1[25];
    {
        const float* vb = vid + (4 * d0) * IW + c0c0 * 4;
#pragma unroll
        for (int kr = 0; kr < 5; ++kr) {
            float4 v = *(const float4*)(vb + kr * IW);
            PX0[kr*5+0]=v.x; PX0[kr*5+1]=v.y; PX0[kr*5+2]=v.z; PX0[kr*5+3]=v.w;
            PX0[kr*5+4]=vb[kr*IW+4];
        }
        if (has1) {
            const float* vc = vid + (4 * d1) * IW + c0c1 * 4;
#pragma unroll
            for (int kr = 0; kr < 5; ++kr) {
                float4 v = *(const float4*)(vc + kr * IW);
                PX1[kr*5+0]=v.x; PX1[kr*5+1]=v.y; PX1[kr*5+2]=v.z; PX1[kr*5+3]=v.w;
                PX1[kr*5+4]=vc[kr*IW+4];
            }
        }
    }
    __syncthreads();

    for (int r1 = 0; r1 < 14; ++r1) {
        {
            float acc[16];
            {
                const float4* b4 = (const float4*)&W0T[25 * 16];
                float4 ba = b4[0], bb = b4[1], bc = b4[2], bd = b4[3];
                acc[0]=ba.x; acc[1]=ba.y; acc[2]=ba.z; acc[3]=ba.w;
                acc[4]=bb.x; acc[5]=bb.y; acc[6]=bb.z; acc[7]=bb.w;
                acc[8]=bc.x; acc[9]=bc.y; acc[10]=bc.z; acc[11]=bc.w;
                acc[12]=bd.x; acc[13]=bd.y; acc[14]=bd.z; acc[15]=bd.w;
            }
#pragma unroll
            for (int tap = 0; tap < 25; ++tap) {
                float p = PX0[tap];
                const float4* w4 = (const float4*)&W0T[tap * 16];
                float4 wa = w4[0], wb = w4[1], wc = w4[2], wd = w4[3];
                acc[0]+=p*wa.x; acc[1]+=p*wa.y; acc[2]+=p*wa.z; acc[3]+=p*wa.w;
                acc[4]+=p*wb.x; acc[5]+=p*wb.y; acc[6]+=p*wb.z; acc[7]+=p*wb.w;
                acc[8]+=p*wc.x; acc[9]+=p*wc.y; acc[10]+=p*wc.z; acc[11]+=p*wc.w;
                acc[12]+=p*wd.x; acc[13]+=p*wd.y; acc[14]+=p*wd.z; acc[15]+=p*wd.w;
            }
#pragma unroll
            for (int ch = 0; ch < 16; ++ch)
                band[ch * 408 + d0 * 80 + c0c0] = fmaxf(acc[ch], 0.f);
        }
        if (has1) {
            float acc[16];
            {
                const float4* b4 = (const float4*)&W0T[25 * 16];
                float4 ba = b4[0], bb = b4[1], bc = b4[2], bd = b4[3];
                acc[0]=ba.x; acc[1]=ba.y; acc[2]=ba.z; acc[3]=ba.w;
                acc[4]=bb.x; acc[5]=bb.y; acc[6]=bb.z; acc[7]=bb.w;
                acc[8]=bc.x; acc[9]=bc.y; acc[10]=bc.z; acc[11]=bc.w;
                acc[12]=bd.x; acc[13]=bd.y; acc[14]=bd.z; acc[15]=bd.w;
            }
#pragma unroll
            for (int tap = 0; tap < 25; ++tap) {
                float p = PX1[tap];
                const float4* w4 = (const float4*)&W0T[tap * 16];
                float4 wa = w4[0], wb = w4[1], wc = w4[2], wd = w4[3];
                acc[0]+=p*wa.x; acc[1]+=p*wa.y; acc[2]+=p*wa.z; acc[3]+=p*wa.w;
                acc[4]+=p*wb.x; acc[5]+=p*wb.y; acc[6]+=p*wb.z; acc[7]+=p*wb.w;
                acc[8]+=p*wc.x; acc[9]+=p*wc.y; acc[10]+=p*wc.z; acc[11]+=p*wc.w;
                acc[12]+=p*wd.x; acc[13]+=p*wd.y; acc[14]+=p*wd.z; acc[15]+=p*wd.w;
            }
#pragma unroll
            for (int ch = 0; ch < 16; ++ch)
                band[ch * 408 + d1 * 80 + c0c1] = fmaxf(acc[ch], 0.f);
        }

        if (r1 + 1 < 14) {
            const float* vb = vid + (16 * (r1+1) + 4 * d0) * IW + c0c0 * 4;
#pragma unroll
            for (int kr = 0; kr < 5; ++kr) {
                float4 v = *(const float4*)(vb + kr * IW);
                PX0[kr*5+0]=v.x; PX0[kr*5+1]=v.y; PX0[kr*5+2]=v.z; PX0[kr*5+3]=v.w;
                PX0[kr*5+4]=vb[kr*IW+4];
            }
            if (has1) {
                const float* vc = vid + (16 * (r1+1) + 4 * d1) * IW + c0c1 * 4;
#pragma unroll
                for (int kr = 0; kr < 5; ++kr) {
                    float4 v = *(const float4*)(vc + kr * IW);
                    PX1[kr*5+0]=v.x; PX1[kr*5+1]=v.y; PX1[kr*5+2]=v.z; PX1[kr*5+3]=v.w;
                    PX1[kr*5+4]=vc[kr*IW+4];
                }
            }
        }
        __syncthreads();

        const float* bb0 = &band[ic * 408];
        for (int c1c = 0; c1c < 19; ++c1c) {
            const float* bb = bb0 + c1c * 4;
            float a0, a1, a2, a3, a4;
            {
                float4 v = *(const float4*)(bb);       float sc = bb[4];
                a0 = v.x*w1r[0]  + v.y*w1r[1]  + v.z*w1r[2]  + v.w*w1r[3]  + sc*w1r[4];
            }
            {
                float4 v = *(const float4*)(bb + 80);  float sc = bb[84];
                a1 = v.x*w1r[5]  + v.y*w1r[6]  + v.z*w1r[7]  + v.w*w1r[8]  + sc*w1r[9];
            }
            {
                float4 v = *(const float4*)(bb + 160); float sc = bb[164];
                a2 = v.x*w1r[10] + v.y*w1r[11] + v.z*w1r[12] + v.w*w1r[13] + sc*w1r[14];
            }
            {
                float4 v = *(const float4*)(bb + 240); float sc = bb[244];
                a3 = v.x*w1r[15] + v.y*w1r[16] + v.z*w1r[17] + v.w*w1r[18] + sc*w1r[19];
            }
            {
                float4 v = *(const float4*)(bb + 320); float sc = bb[324];
                a4 = v.x*w1r[20] + v.y*w1r[21] + v.z*w1r[22] + v.w*w1r[23] + sc*w1r[24];
            }
            float p = ((a0 + a1) + (a2 + a3)) + a4;
            p += __shfl_xor(p, 16);
            p += __shfl_xor(p, 32);
            if (lane < 16)
                part[c1c * 68 + wave * 17 + ch1] = p;
        }
        __syncthreads();

        for (int o = tid; o < 304; o += 256) {
            int c1c = o >> 4, ch = o & 15;
            const float* pp = &part[c1c * 68 + ch];
            float v = bc1[ch] + pp[0] + pp[17] + pp[34] + pp[51];
            c1L[(r1 * 19 + c1c) * 17 + ch] = fmaxf(v, 0.f);
        }
        __syncthreads();
    }

    for (int o = tid; o < 252; o += 256) {
        int ch2 = o / 63, rr = (o / 9) % 7, cc = o % 9;
        float a = bc2[ch2];
        for (int ic2 = 0; ic2 < 16; ++ic2)
            for (int kr = 0; kr < 2; ++kr)
                for (int kc = 0; kc < 2; ++kc)
                    a += c1L[((2 * rr + kr) * 19 + 2 * cc + kc) * 17 + ic2] *
                         Wc2[((ch2 * 16 + ic2) * 2 + kr) * 2 + kc];
        X[(size_t)s * XDIM + 64 + o] = fmaxf(a, 0.f);
    }
}

// ---------------------------------------------------------------- K3: G = X @ Wih^T + bih + bhh (float4, 4 chains)
__global__ void k_gpre(const float* __restrict__ X, const float* __restrict__ Wih,
                       const float* __restrict__ bih, const float* __restrict__ bhh,
                       float* __restrict__ G) {
    int s = blockIdx.x;
    int j = threadIdx.x;
    const float4* x4 = (const float4*)(X + (size_t)s * XDIM);
    const float4* w4 = (const float4*)(Wih + (size_t)j * XDIM);
    float a0 = 0.f, a1 = 0.f, a2 = 0.f, a3 = 0.f;
    for (int ko = 0; ko < 79; ++ko) {
        float4 w = w4[ko], x = x4[ko];
        a0 += w.x * x.x;
        a1 += w.y * x.y;
        a2 += w.z * x.z;
        a3 += w.w * x.w;
    }
    G[(size_t)s * 256 + j] = ((a0 + a1) + (a2 + a3)) + (bih[j] + bhh[j]);
}

// ---------------------------------------------------------------- K4: LSTM scan — 4-wave SPLIT-K, shared-broadcast matvec
// R10: R8==R9 proved the fused floor was producer delivery, not the scan
// -> revert to split kernels (producers at full 3/CU throughput). Scan:
// R5's step = ~600cy issue + ~530cy exchange. Cut issue: wave w computes
// ALL 4 gates over taps [16w,16w+16) -> only 16 readlanes per step
// (shared across the 4 gates' FMAs) + 64 fma. Weights 64 floats/lane
// (16 named float4, R5-proven residency size). Exchange keeps the proven
// single-barrier pattern: 4 ds_write_b32 partials (stride-4B, conflict-
// free), barrier, 16 stride-64B b32 reads + fixed-tree sums; activations
// replicated x4 waves (~40 inst — R6's regression was 2 waves/SIMD, not
// replication). Predicted step ~850cy vs 1130.
__global__ __launch_bounds__(256, 1) void k_scan(const float* __restrict__ G,
        const float* __restrict__ Whh,
        const float* __restrict__ W10, const float* __restrict__ b10,
        const float* __restrict__ W11, const float* __restrict__ b11,
        const float* __restrict__ W12, const float* __restrict__ b12,
        float* __restrict__ out) {
    __shared__ float prt[2][4 * 256];    // [buf][gate*256 + w*64 + l]
    __shared__ float hsL[16 * 64];
    __shared__ float m1s[32], m2s[32];
    int j = threadIdx.x;
    int w = j >> 6, l = j & 63;
    int kb = w << 4;                     // this wave's tap base: 16w

    // weights: gate g, quad q -> Whh[(g*64+l)*64 + kb + 4q], 16 named float4
    float4 wA0, wA1, wA2, wA3, wB0, wB1, wB2, wB3;
    float4 wC0, wC1, wC2, wC3, wD0, wD1, wD2, wD3;
    {
        const float* ra = Whh + (size_t)(0 * 64 + l) * 64 + kb;
        const float* rb = Whh + (size_t)(1 * 64 + l) * 64 + kb;
        const float* rc = Whh + (size_t)(2 * 64 + l) * 64 + kb;
        const float* rd = Whh + (size_t)(3 * 64 + l) * 64 + kb;
        wA0 = *(const float4*)(ra);      wA1 = *(const float4*)(ra + 4);
        wA2 = *(const float4*)(ra + 8);  wA3 = *(const float4*)(ra + 12);
        wB0 = *(const float4*)(rb);      wB1 = *(const float4*)(rb + 4);
        wB2 = *(const float4*)(rb + 8);  wB3 = *(const float4*)(rb + 12);
        wC0 = *(const float4*)(rc);      wC1 = *(const float4*)(rc + 4);
        wC2 = *(const float4*)(rc + 8);  wC3 = *(const float4*)(rc + 12);
        wD0 = *(const float4*)(rd);      wD1 = *(const float4*)(rd + 4);
        wD2 = *(const float4*)(rd + 8);  wD3 = *(const float4*)(rd + 12);
    }

    float h = 0.f, c = 0.f;              // replicated: lane l holds h[l],c[l]
    // wave w's own G row is gate w (j = w*64+l in [s][gate*64+l] layout)
    float gc = G[j];
    float gn = G[256 + j];

    for (int t = 0; t < NSEQ; ++t) {
        int t2 = (t + 2 < NSEQ) ? t + 2 : NSEQ - 1;
        float gp = G[(size_t)t2 * 256 + j];          // prefetch depth 2

        // per-gate partials over taps [kb, kb+16); gc folded into owning gate
        float pA0 = (w == 0) ? gc : 0.f, pA1 = 0.f;
        float pB0 = (w == 1) ? gc : 0.f, pB1 = 0.f;
        float pC0 = (w == 2) ? gc : 0.f, pC1 = 0.f;
        float pD0 = (w == 3) ? gc : 0.f, pD1 = 0.f;
#define QUAD(q) { \
        float h0 = rl(h, kb + 4*(q) + 0), h1 = rl(h, kb + 4*(q) + 1); \
        float h2 = rl(h, kb + 4*(q) + 2), h3 = rl(h, kb + 4*(q) + 3); \
        pA0 += h0 * wA##q.x; pA1 += h1 * wA##q.y; pA0 += h2 * wA##q.z; pA1 += h3 * wA##q.w; \
        pB0 += h0 * wB##q.x; pB1 += h1 * wB##q.y; pB0 += h2 * wB##q.z; pB1 += h3 * wB##q.w; \
        pC0 += h0 * wC##q.x; pC1 += h1 * wC##q.y; pC0 += h2 * wC##q.z; pC1 += h3 * wC##q.w; \
        pD0 += h0 * wD##q.x; pD1 += h1 * wD##q.y; pD0 += h2 * wD##q.z; pD1 += h3 * wD##q.w; \
    }
        QUAD(0) QUAD(1) QUAD(2) QUAD(3)
#undef QUAD

        float* pb = &prt[t & 1][0];
        pb[0 * 256 + (w << 6) + l] = pA0 + pA1;      // stride-4B writes: conflict-free
        pb[1 * 256 + (w << 6) + l] = pB0 + pB1;
        pb[2 * 256 + (w << 6) + l] = pC0 + pC1;
        pb[3 * 256 + (w << 6) + l] = pD0 + pD1;
        asm volatile("s_waitcnt lgkmcnt(0)\n\ts_barrier" ::: "memory");
        const float* rb = &prt[t & 1][0];
        float ai = (rb[l]       + rb[64 + l])  + (rb[128 + l] + rb[192 + l]);
        float af = (rb[256 + l] + rb[320 + l]) + (rb[384 + l] + rb[448 + l]);
        float ag = (rb[512 + l] + rb[576 + l]) + (rb[640 + l] + rb[704 + l]);
        float ao = (rb[768 + l] + rb[832 + l]) + (rb[896 + l] + rb[960 + l]);
        ai = sig_f(ai); af = sig_f(af); ag = tanh_f(ag); ao = sig_f(ao);
        c = af * c + ai * ag;
        h = ao * tanh_f(c);
        if (t >= NSEQ - 16 && w == 0) hsL[(t - (NSEQ - 16)) * 64 + l] = h;
        gc = gn; gn = gp;
    }
    __syncthreads();

    // output head: 16 rows x (64->32->32->256)
    for (int r = 0; r < 16; ++r) {
        if (j < 32) {
            float a = b10[j];
            for (int k = 0; k < 64; ++k) a += hsL[r * 64 + k] * W10[j * 64 + k];
            m1s[j] = fmaxf(a, 0.f);
        }
        __syncthreads();
        if (j < 32) {
            float a = b11[j];
            for (int k = 0; k < 32; ++k) a += m1s[k] * W11[j * 32 + k];
            m2s[j] = fmaxf(a, 0.f);
        }
        __syncthreads();
        {
            float a = b12[j];
            for (int k = 0; k < 32; ++k) a += m2s[k] * W12[j * 32 + k];
            out[r * 256 + j] = a;
        }
        __syncthreads();
    }
}

// ---------------------------------------------------------------- launch
extern "C" void kernel_launch(void* const* d_in, const int* in_sizes, int n_in,
                              void* d_out, int out_size, void* d_ws, size_t ws_size,
                              hipStream_t stream) {
    const float* inp   = (const float*)d_in[0];
    const float* video = (const float*)d_in[1];
    const float* W00   = (const float*)d_in[2];
    const float* b00   = (const float*)d_in[3];
    const float* W01   = (const float*)d_in[4];
    const float* b01   = (const float*)d_in[5];
    const float* Wc0   = (const float*)d_in[6];
    const float* bc0   = (const float*)d_in[7];
    const float* Wc1   = (const float*)d_in[8];
    const float* bc1   = (const float*)d_in[9];
    const float* Wc2   = (const float*)d_in[10];
    const float* bc2   = (const float*)d_in[11];
    const float* Wih   = (const float*)d_in[12];
    const float* Whh   = (const float*)d_in[13];
    const float* bih   = (const float*)d_in[14];
    const float* bhh   = (const float*)d_in[15];
    const float* W10   = (const float*)d_in[16];
    const float* b10   = (const float*)d_in[17];
    const float* W11   = (const float*)d_in[18];
    const float* b11   = (const float*)d_in[19];
    const float* W12   = (const float*)d_in[20];
    const float* b12   = (const float*)d_in[21];

    float* X = (float*)d_ws;
    float* G = (float*)((char*)d_ws + X_BYTES);

    k_mlp <<<NSEQ, 64, 0, stream>>>(inp, W00, b00, W01, b01, X);
    k_conv<<<NSEQ, 256, 0, stream>>>(video, Wc0, bc0, Wc1, bc1, Wc2, bc2, X);
    k_gpre<<<NSEQ, 256, 0, stream>>>(X, Wih, bih, bhh, G);
    k_scan<<<1, 256, 0, stream>>>(G, Whh, W10, b10, W11, b11, W12, b12, (float*)d_out);
}

// Round 11
// 715.780 us; speedup vs baseline: 1.1644x; 1.1644x over previous
//
#include <hip/hip_runtime.h>
#include <math.h>

#define B_   16
#define T_   60
#define LMD  63
#define IH   240
#define IW   320
#define XDIM 316
#define NSEQ 960

#define X_BYTES   1213440                   // 960*316*4
#define G_BYTES   983040                    // 960*256*4

__device__ __forceinline__ float rl(float v, int k) {
    return __uint_as_float((unsigned)__builtin_amdgcn_readlane((int)__float_as_uint(v), k));
}
// Fast gates (v_exp + v_rcp): verified R21 — absmax identical to libm (9.5e-7).
__device__ __forceinline__ float sig_f(float x) {
    return __builtin_amdgcn_rcpf(1.0f + __expf(-x));
}
__device__ __forceinline__ float tanh_f(float x) {
    return 1.0f - 2.0f * __builtin_amdgcn_rcpf(__expf(2.0f * x) + 1.0f);
}

// ---------------------------------------------------------------- K1: f-MLP (LDS broadcast, 4 accum chains)
__global__ void k_mlp(const float* __restrict__ inp,
                      const float* __restrict__ W00, const float* __restrict__ b00,
                      const float* __restrict__ W01, const float* __restrict__ b01,
                      float* __restrict__ X) {
    __shared__ float x0s[LMD], f1s[LMD];
    int bt = blockIdx.x;
    int b = bt / T_, t = bt % T_;
    int s = t * B_ + b;
    int m = threadIdx.x;                 // 0..63
    if (m < LMD) x0s[m] = inp[bt * LMD + m];
    __syncthreads();
    if (m < LMD) {
        const float* wr = W00 + m * LMD;
        float a0 = 0.f, a1 = 0.f, a2 = 0.f, a3 = 0.f;
        for (int k = 0; k < 60; k += 4) {
            a0 += x0s[k + 0] * wr[k + 0];
            a1 += x0s[k + 1] * wr[k + 1];
            a2 += x0s[k + 2] * wr[k + 2];
            a3 += x0s[k + 3] * wr[k + 3];
        }
        a0 += x0s[60] * wr[60]; a1 += x0s[61] * wr[61]; a2 += x0s[62] * wr[62];
        f1s[m] = fmaxf(((a0 + a1) + (a2 + a3)) + b00[m], 0.f);
    }
    __syncthreads();
    {
        const float* wr = W01 + m * LMD;
        float a0 = 0.f, a1 = 0.f, a2 = 0.f, a3 = 0.f;
        for (int k = 0; k < 60; k += 4) {
            a0 += f1s[k + 0] * wr[k + 0];
            a1 += f1s[k + 1] * wr[k + 1];
            a2 += f1s[k + 2] * wr[k + 2];
            a3 += f1s[k + 3] * wr[k + 3];
        }
        a0 += f1s[60] * wr[60]; a1 += f1s[61] * wr[61]; a2 += f1s[62] * wr[62];
        X[(size_t)s * XDIM + m] = fmaxf(((a0 + a1) + (a2 + a3)) + b01[m], 0.f);
    }
}

// ---------------------------------------------------------------- K2: conv stack — video-load pipeline + wave ic-reduce
__global__ __launch_bounds__(256, 1) void k_conv(const float* __restrict__ video,
        const float* __restrict__ Wc0, const float* __restrict__ bc0,
        const float* __restrict__ Wc1, const float* __restrict__ bc1,
        const float* __restrict__ Wc2, const float* __restrict__ bc2,
        float* __restrict__ X) {
    __shared__ float W0T[26 * 16];         // [tap][ch]; row 25 = bc0
    __shared__ float band[16 * 408];       // [ic][d*80 + c0c]
    __shared__ float part[19 * 4 * 17];    // [c1c][wave][ch1], pad 17
    __shared__ float c1L[14 * 19 * 17];    // [(r1*19 + c1c)*17 + ch]
    int tid = threadIdx.x;
    int bt = blockIdx.x;
    int b = bt / T_, t = bt % T_;
    int s = t * B_ + b;
    const float* vid = video + (size_t)bt * (IH * IW);

    int ch1 = tid & 15, ic = tid >> 4;
    int wave = tid >> 6, lane = tid & 63;

    int d0 = tid / 79, c0c0 = tid % 79;
    int pos1 = tid + 256;
    bool has1 = (pos1 < 395);
    int d1 = has1 ? pos1 / 79 : 0, c0c1 = has1 ? pos1 % 79 : 0;

    for (int i = tid; i < 400; i += 256) { int ch = i / 25, tap = i % 25; W0T[tap * 16 + ch] = Wc0[i]; }
    if (tid < 16) W0T[25 * 16 + tid] = bc0[tid];
    float w1r[25];
#pragma unroll
    for (int tap = 0; tap < 25; ++tap)
        w1r[tap] = Wc1[(ch1 * 16 + ic) * 25 + tap];

    float PX0[25], PX1[25];
    {
        const float* vb = vid + (4 * d0) * IW + c0c0 * 4;
#pragma unroll
        for (int kr = 0; kr < 5; ++kr) {
            float4 v = *(const float4*)(vb + kr * IW);
            PX0[kr*5+0]=v.x; PX0[kr*5+1]=v.y; PX0[kr*5+2]=v.z; PX0[kr*5+3]=v.w;
            PX0[kr*5+4]=vb[kr*IW+4];
        }
        if (has1) {
            const float* vc = vid + (4 * d1) * IW + c0c1 * 4;
#pragma unroll
            for (int kr = 0; kr < 5; ++kr) {
                float4 v = *(const float4*)(vc + kr * IW);
                PX1[kr*5+0]=v.x; PX1[kr*5+1]=v.y; PX1[kr*5+2]=v.z; PX1[kr*5+3]=v.w;
                PX1[kr*5+4]=vc[kr*IW+4];
            }
        }
    }
    __syncthreads();

    for (int r1 = 0; r1 < 14; ++r1) {
        {
            float acc[16];
            {
                const float4* b4 = (const float4*)&W0T[25 * 16];
                float4 ba = b4[0], bb = b4[1], bc = b4[2], bd = b4[3];
                acc[0]=ba.x; acc[1]=ba.y; acc[2]=ba.z; acc[3]=ba.w;
                acc[4]=bb.x; acc[5]=bb.y; acc[6]=bb.z; acc[7]=bb.w;
                acc[8]=bc.x; acc[9]=bc.y; acc[10]=bc.z; acc[11]=bc.w;
                acc[12]=bd.x; acc[13]=bd.y; acc[14]=bd.z; acc[15]=bd.w;
            }
#pragma unroll
            for (int tap = 0; tap < 25; ++tap) {
                float p = PX0[tap];
                const float4* w4 = (const float4*)&W0T[tap * 16];
                float4 wa = w4[0], wb = w4[1], wc = w4[2], wd = w4[3];
                acc[0]+=p*wa.x; acc[1]+=p*wa.y; acc[2]+=p*wa.z; acc[3]+=p*wa.w;
                acc[4]+=p*wb.x; acc[5]+=p*wb.y; acc[6]+=p*wb.z; acc[7]+=p*wb.w;
                acc[8]+=p*wc.x; acc[9]+=p*wc.y; acc[10]+=p*wc.z; acc[11]+=p*wc.w;
                acc[12]+=p*wd.x; acc[13]+=p*wd.y; acc[14]+=p*wd.z; acc[15]+=p*wd.w;
            }
#pragma unroll
            for (int ch = 0; ch < 16; ++ch)
                band[ch * 408 + d0 * 80 + c0c0] = fmaxf(acc[ch], 0.f);
        }
        if (has1) {
            float acc[16];
            {
                const float4* b4 = (const float4*)&W0T[25 * 16];
                float4 ba = b4[0], bb = b4[1], bc = b4[2], bd = b4[3];
                acc[0]=ba.x; acc[1]=ba.y; acc[2]=ba.z; acc[3]=ba.w;
                acc[4]=bb.x; acc[5]=bb.y; acc[6]=bb.z; acc[7]=bb.w;
                acc[8]=bc.x; acc[9]=bc.y; acc[10]=bc.z; acc[11]=bc.w;
                acc[12]=bd.x; acc[13]=bd.y; acc[14]=bd.z; acc[15]=bd.w;
            }
#pragma unroll
            for (int tap = 0; tap < 25; ++tap) {
                float p = PX1[tap];
                const float4* w4 = (const float4*)&W0T[tap * 16];
                float4 wa = w4[0], wb = w4[1], wc = w4[2], wd = w4[3];
                acc[0]+=p*wa.x; acc[1]+=p*wa.y; acc[2]+=p*wa.z; acc[3]+=p*wa.w;
                acc[4]+=p*wb.x; acc[5]+=p*wb.y; acc[6]+=p*wb.z; acc[7]+=p*wb.w;
                acc[8]+=p*wc.x; acc[9]+=p*wc.y; acc[10]+=p*wc.z; acc[11]+=p*wc.w;
                acc[12]+=p*wd.x; acc[13]+=p*wd.y; acc[14]+=p*wd.z; acc[15]+=p*wd.w;
            }
#pragma unroll
            for (int ch = 0; ch < 16; ++ch)
                band[ch * 408 + d1 * 80 + c0c1] = fmaxf(acc[ch], 0.f);
        }

        if (r1 + 1 < 14) {
            const float* vb = vid + (16 * (r1+1) + 4 * d0) * IW + c0c0 * 4;
#pragma unroll
            for (int kr = 0; kr < 5; ++kr) {
                float4 v = *(const float4*)(vb + kr * IW);
                PX0[kr*5+0]=v.x; PX0[kr*5+1]=v.y; PX0[kr*5+2]=v.z; PX0[kr*5+3]=v.w;
                PX0[kr*5+4]=vb[kr*IW+4];
            }
            if (has1) {
                const float* vc = vid + (16 * (r1+1) + 4 * d1) * IW + c0c1 * 4;
#pragma unroll
                for (int kr = 0; kr < 5; ++kr) {
                    float4 v = *(const float4*)(vc + kr * IW);
                    PX1[kr*5+0]=v.x; PX1[kr*5+1]=v.y; PX1[kr*5+2]=v.z; PX1[kr*5+3]=v.w;
                    PX1[kr*5+4]=vc[kr*IW+4];
                }
            }
        }
        __syncthreads();

        const float* bb0 = &band[ic * 408];
        for (int c1c = 0; c1c < 19; ++c1c) {
            const float* bb = bb0 + c1c * 4;
            float a0, a1, a2, a3, a4;
            {
                float4 v = *(const float4*)(bb);       float sc = bb[4];
                a0 = v.x*w1r[0]  + v.y*w1r[1]  + v.z*w1r[2]  + v.w*w1r[3]  + sc*w1r[4];
            }
            {
                float4 v = *(const float4*)(bb + 80);  float sc = bb[84];
                a1 = v.x*w1r[5]  + v.y*w1r[6]  + v.z*w1r[7]  + v.w*w1r[8]  + sc*w1r[9];
            }
            {
                float4 v = *(const float4*)(bb + 160); float sc = bb[164];
                a2 = v.x*w1r[10] + v.y*w1r[11] + v.z*w1r[12] + v.w*w1r[13] + sc*w1r[14];
            }
            {
                float4 v = *(const float4*)(bb + 240); float sc = bb[244];
                a3 = v.x*w1r[15] + v.y*w1r[16] + v.z*w1r[17] + v.w*w1r[18] + sc*w1r[19];
            }
            {
                float4 v = *(const float4*)(bb + 320); float sc = bb[324];
                a4 = v.x*w1r[20] + v.y*w1r[21] + v.z*w1r[22] + v.w*w1r[23] + sc*w1r[24];
            }
            float p = ((a0 + a1) + (a2 + a3)) + a4;
            p += __shfl_xor(p, 16);
            p += __shfl_xor(p, 32);
            if (lane < 16)
                part[c1c * 68 + wave * 17 + ch1] = p;
        }
        __syncthreads();

        for (int o = tid; o < 304; o += 256) {
            int c1c = o >> 4, ch = o & 15;
            const float* pp = &part[c1c * 68 + ch];
            float v = bc1[ch] + pp[0] + pp[17] + pp[34] + pp[51];
            c1L[(r1 * 19 + c1c) * 17 + ch] = fmaxf(v, 0.f);
        }
        __syncthreads();
    }

    for (int o = tid; o < 252; o += 256) {
        int ch2 = o / 63, rr = (o / 9) % 7, cc = o % 9;
        float a = bc2[ch2];
        for (int ic2 = 0; ic2 < 16; ++ic2)
            for (int kr = 0; kr < 2; ++kr)
                for (int kc = 0; kc < 2; ++kc)
                    a += c1L[((2 * rr + kr) * 19 + 2 * cc + kc) * 17 + ic2] *
                         Wc2[((ch2 * 16 + ic2) * 2 + kr) * 2 + kc];
        X[(size_t)s * XDIM + 64 + o] = fmaxf(a, 0.f);
    }
}

// ---------------------------------------------------------------- K3: G = X @ Wih^T + bih + bhh (float4, 4 chains)
__global__ void k_gpre(const float* __restrict__ X, const float* __restrict__ Wih,
                       const float* __restrict__ bih, const float* __restrict__ bhh,
                       float* __restrict__ G) {
    int s = blockIdx.x;
    int j = threadIdx.x;
    const float4* x4 = (const float4*)(X + (size_t)s * XDIM);
    const float4* w4 = (const float4*)(Wih + (size_t)j * XDIM);
    float a0 = 0.f, a1 = 0.f, a2 = 0.f, a3 = 0.f;
    for (int ko = 0; ko < 79; ++ko) {
        float4 w = w4[ko], x = x4[ko];
        a0 += w.x * x.x;
        a1 += w.y * x.y;
        a2 += w.z * x.z;
        a3 += w.w * x.w;
    }
    G[(size_t)s * 256 + j] = ((a0 + a1) + (a2 + a3)) + (bih[j] + bhh[j]);
}

// ---------------------------------------------------------------- K4: LSTM scan — R5 structure + waves_per_eu(1,1)
// R11: R10 proved the exchange tail is latency-critical -> R5's shape
// (act pre-barrier, 4-read tail) is right. Remaining measured fat: R5's
// VALUBusy implies ~300 inst/wave/step vs ~170 visible -> ~64 extra ops
// = per-use v_accvgpr_read of the AGPR-parked weights (VGPR_Count=64:
// allocator optimized for occupancy this 1-block kernel can't use).
// amdgpu_waves_per_eu(1,1) caps max waves/EU at 1 -> arch VGPRs are
// free -> weights should become arch-resident, deleting the AGPR copies.
// Verification: VGPR_Count >= 128. Loop split at t=944 removes the
// per-step hsL branch + prefetch clamp from the main 944 steps.
#define REPW(M) M(0) M(1) M(2) M(3) M(4) M(5) M(6) M(7) \
                M(8) M(9) M(10) M(11) M(12) M(13) M(14) M(15)

__global__ __launch_bounds__(256)
__attribute__((amdgpu_waves_per_eu(1, 1)))
void k_scan(const float* __restrict__ G,
        const float* __restrict__ Whh,
        const float* __restrict__ W10, const float* __restrict__ b10,
        const float* __restrict__ W11, const float* __restrict__ b11,
        const float* __restrict__ W12, const float* __restrict__ b12,
        float* __restrict__ out) {
    __shared__ float act[2][256];
    __shared__ float hsL[16 * 64];
    __shared__ float m1s[32], m2s[32];
    int j = threadIdx.x;
    int w = j >> 6, l = j & 63;

    // thread j owns gate-output j: its Whh row, 16 named float4s (64 regs)
#define DECLW(n) float4 wv##n;
    REPW(DECLW)
#undef DECLW
    {
        const float4* Wr = (const float4*)(Whh + (size_t)j * 64);
#define LOADW(n) wv##n = Wr[n];
        REPW(LOADW)
#undef LOADW
    }

    float h = 0.f, c = 0.f;                  // replicated per wave: lane l holds h[l],c[l]
    float gcur = G[j];

#define STEPBODY(GNEXT_EXPR)                                              \
    {                                                                     \
        float gnext = (GNEXT_EXPR);                                       \
        float a0 = gcur, a1 = 0.f, a2 = 0.f, a3 = 0.f;                    \
        REPW(GFMA)                                                        \
        float g = (a0 + a1) + (a2 + a3);                                  \
        float av = (w == 2) ? tanh_f(g) : sig_f(g);                       \
        act[t & 1][j] = av;                                               \
        asm volatile("s_waitcnt lgkmcnt(0)\n\ts_barrier" ::: "memory");   \
        const float* ab = act[t & 1];                                     \
        float ai = ab[l], af = ab[64 + l], ag = ab[128 + l], ao = ab[192 + l]; \
        c = af * c + ai * ag;                                             \
        h = ao * tanh_f(c);                                               \
        gcur = gnext;                                                     \
    }
#define GFMA(n) {                                                         \
        float h0 = rl(h, 4*(n)+0), h1 = rl(h, 4*(n)+1);                   \
        float h2 = rl(h, 4*(n)+2), h3 = rl(h, 4*(n)+3);                   \
        a0 += h0 * wv##n.x; a1 += h1 * wv##n.y;                           \
        a2 += h2 * wv##n.z; a3 += h3 * wv##n.w;                           \
    }

    // main: t = 0..943 — no hsL branch, unconditional prefetch
    for (int t = 0; t < NSEQ - 16; ++t) {
        STEPBODY(G[(size_t)(t + 1) * 256 + j])
    }
    // tail: t = 944..959 — hsL stores, clamped prefetch
    for (int t = NSEQ - 16; t < NSEQ; ++t) {
        STEPBODY((t + 1 < NSEQ) ? G[(size_t)(t + 1) * 256 + j] : 0.f)
        if (w == 0) hsL[(t - (NSEQ - 16)) * 64 + l] = h;
    }
#undef GFMA
#undef STEPBODY
    __syncthreads();

    // output head: 16 rows x (64->32->32->256)
    for (int r = 0; r < 16; ++r) {
        if (j < 32) {
            float a = b10[j];
            for (int k = 0; k < 64; ++k) a += hsL[r * 64 + k] * W10[j * 64 + k];
            m1s[j] = fmaxf(a, 0.f);
        }
        __syncthreads();
        if (j < 32) {
            float a = b11[j];
            for (int k = 0; k < 32; ++k) a += m1s[k] * W11[j * 32 + k];
            m2s[j] = fmaxf(a, 0.f);
        }
        __syncthreads();
        {
            float a = b12[j];
            for (int k = 0; k < 32; ++k) a += m2s[k] * W12[j * 32 + k];
            out[r * 256 + j] = a;
        }
        __syncthreads();
    }
}

// ---------------------------------------------------------------- launch
extern "C" void kernel_launch(void* const* d_in, const int* in_sizes, int n_in,
                              void* d_out, int out_size, void* d_ws, size_t ws_size,
                              hipStream_t stream) {
    const float* inp   = (const float*)d_in[0];
    const float* video = (const float*)d_in[1];
    const float* W00   = (const float*)d_in[2];
    const float* b00   = (const float*)d_in[3];
    const float* W01   = (const float*)d_in[4];
    const float* b01   = (const float*)d_in[5];
    const float* Wc0   = (const float*)d_in[6];
    const float* bc0   = (const float*)d_in[7];
    const float* Wc1   = (const float*)d_in[8];
    const float* bc1   = (const float*)d_in[9];
    const float* Wc2   = (const float*)d_in[10];
    const float* bc2   = (const float*)d_in[11];
    const float* Wih   = (const float*)d_in[12];
    const float* Whh   = (const float*)d_in[13];
    const float* bih   = (const float*)d_in[14];
    const float* bhh   = (const float*)d_in[15];
    const float* W10   = (const float*)d_in[16];
    const float* b10   = (const float*)d_in[17];
    const float* W11   = (const float*)d_in[18];
    const float* b11   = (const float*)d_in[19];
    const float* W12   = (const float*)d_in[20];
    const float* b12   = (const float*)d_in[21];

    float* X = (float*)d_ws;
    float* G = (float*)((char*)d_ws + X_BYTES);

    k_mlp <<<NSEQ, 64, 0, stream>>>(inp, W00, b00, W01, b01, X);
    k_conv<<<NSEQ, 256, 0, stream>>>(video, Wc0, bc0, Wc1, bc1, Wc2, bc2, X);
    k_gpre<<<NSEQ, 256, 0, stream>>>(X, Wih, bih, bhh, G);
    k_scan<<<1, 256, 0, stream>>>(G, Whh, W10, b10, W11, b11, W12, b12, (float*)d_out);
}